// Round 12
// baseline (390.130 us; speedup 1.0000x reference)
//
#include <hip/hip_runtime.h>
#include <hip/hip_bf16.h>

// Hopfield forward, blocked factored Gauss-Seidel.
// Round 12: r10 structure + T14 async-stage split (issue next group's loads
// into registers at group top, write to LDS after last barrier of the group).
// Plus k_probe: 128 serially-dependent copies of the exact 64-step chain to
// measure its true cost (runs last, writes only ws scratch).

#define OFF_COLB   0u                       // u64 [8][4096]  colbitsP
#define OFF_XBITS  (256u<<10)               // u64 [512][64]  row bits
#define OFF_XBW    (512u<<10)               // u64 [64][512]  xbitsW
#define OFF_KF     (768u<<10)               // f32 [64][64][64] Kdiag : 1 MB
#define OFF_BCORR  (1792u<<10)              // f32 [4096] baseCorr
#define OFF_U      (1808u<<10)              // f32 [64][512] U
#define OFF_CST    (1936u<<10)              // float4 [4096]
#define OFF_P0     (2000u<<10)              // f32 [512]
#define OFF_SBITS  (2002u<<10)              // u64 [64]
#define OFF_CNT    (2003u<<10)              // int [4096]
#define OFF_HDR    (2019u<<10)              // f32 [16]
#define OFF_BS0    (2020u<<10)              // f32 [64]
#define OFF_BS0C   (2021u<<10)              // f32 [64]
#define OFF_SCR    (2022u<<10)              // f32 [128] probe sink

template<int CTRL, int RMASK>
__device__ __forceinline__ float dpp_add(float x){
  int t = __builtin_amdgcn_update_dpp(0, __float_as_int(x), CTRL, RMASK, 0xf, true);
  return x + __int_as_float(t);
}
__device__ __forceinline__ float wave_allsum(float x){
  x = dpp_add<0x111,0xf>(x);
  x = dpp_add<0x112,0xf>(x);
  x = dpp_add<0x114,0xf>(x);
  x = dpp_add<0x118,0xf>(x);
  x = dpp_add<0x142,0xa>(x);
  x = dpp_add<0x143,0xc>(x);
  return __int_as_float(__builtin_amdgcn_readlane(__float_as_int(x), 63));
}

// ---- row bits + transposed-block layout
__global__ void k_xbits(const float* __restrict__ llv, unsigned long long* __restrict__ xbits,
                        unsigned long long* __restrict__ xbitsW){
  int w = threadIdx.x >> 6, lane = threadIdx.x & 63;
  int l = blockIdx.x*4 + w;
  unsigned long long myword = 0;
  for (int c = 0; c < 64; ++c){
    float v = llv[(size_t)l*4096 + c*64 + lane];
    unsigned long long b = __ballot(v >= 0.0f);
    if (c == lane) myword = b;
  }
  xbits[(size_t)l*64 + lane] = myword;
  xbitsW[(size_t)lane*512 + l] = myword;
}

// ---- bit transpose
__global__ void k_bitT(const unsigned long long* __restrict__ xbits,
                       unsigned long long* __restrict__ colbitsP){
  int li = blockIdx.x, ii = blockIdx.y, lane = threadIdx.x;
  unsigned long long w = xbits[(size_t)(li*64 + lane)*64 + ii];
  unsigned long long myw = 0;
  for (int j = 0; j < 64; ++j){
    unsigned long long b = __ballot((w >> j) & 1ull);
    if (j == lane) myw = b;
  }
  colbitsP[(size_t)li*4096 + ii*64 + lane] = myw;
}

// ---- column positive counts
__global__ void k_colc(const unsigned long long* __restrict__ colbitsP, int* __restrict__ colcnt){
  int i = blockIdx.x*256 + threadIdx.x;
  int c = 0;
  #pragma unroll
  for (int wl = 0; wl < 8; ++wl) c += __popcll(colbitsP[(size_t)wl*4096 + i]);
  colcnt[i] = c;
}

// ---- rho
__global__ void k_rho(const int* __restrict__ colcnt, float* __restrict__ hdr){
  __shared__ int sh[256];
  int tid = threadIdx.x;
  int s = 0;
  for (int k = tid; k < 4096; k += 256) s += colcnt[k];
  sh[tid] = s; __syncthreads();
  for (int st = 128; st > 0; st >>= 1){
    if (tid < st) sh[tid] += sh[tid + st];
    __syncthreads();
  }
  if (tid == 0){
    int num = 2*sh[0] - 2097152;
    hdr[0] = (float)num * (1.0f/2097152.0f);
  }
}

// ---- per-step constants
__global__ void k_const(const int* __restrict__ colcnt, const float* __restrict__ hdr,
                        const float* __restrict__ s0, float4* __restrict__ cst){
  int i = blockIdx.x*256 + threadIdx.x;
  float rho = hdr[0];
  float c  = (float)(2*colcnt[i] - 512);
  float r2 = rho*rho;
  float q  = 512.0f + 512.0f*r2 - 2.0f*rho*c;
  float s  = s0[i];
  float4 o;
  o.x = q * s;
  o.y = rho*c - 512.0f*r2;
  o.z = 1.0f - s;
  o.w = c;
  cst[i] = o;
}

// ---- diagonal K blocks + baseCorr + block s0 sums (r10 version)
__global__ void k_kdiag(const unsigned long long* __restrict__ colbitsP,
                        const float4* __restrict__ cst, const float* __restrict__ s0,
                        const float* __restrict__ hdr,
                        float* __restrict__ Kf, float* __restrict__ baseCorr,
                        float* __restrict__ blkS0, float* __restrict__ blkS0C){
  __shared__ unsigned long long cb[8][64];
  __shared__ float Kl[64][64];
  __shared__ float cs[64], ss[64];
  int b = blockIdx.x, i0 = b*64, tid = threadIdx.x;  // 256 threads
  for (int k = tid; k < 512; k += 256)
    cb[k>>6][k&63] = colbitsP[(size_t)(k>>6)*4096 + i0 + (k&63)];
  if (tid < 64){ cs[tid] = cst[i0+tid].w; ss[tid] = s0[i0+tid]; }
  __syncthreads();
  float rho = hdr[0];
  float r2t = 512.0f*rho*rho;
  #pragma unroll
  for (int k = 0; k < 16; ++k){
    int q = tid*16 + k;
    int t = q >> 6, j = q & 63;
    int acc = 0;
    #pragma unroll
    for (int wl = 0; wl < 8; ++wl) acc += __popcll(cb[wl][t] ^ cb[wl][j]);
    float G = (float)(512 - 2*acc);
    float kf = G - rho*(cs[t]+cs[j]) + r2t;
    Kl[t][j] = kf;
    Kf[(size_t)b*4096 + q] = kf;
  }
  __syncthreads();
  if (tid < 64){
    float bc = 0.0f;
    for (int j = 0; j < tid; ++j) bc = fmaf(ss[j], Kl[tid][j], bc);
    baseCorr[i0 + tid] = bc;
  }
  if (tid == 64){
    float a = 0.0f, b2 = 0.0f;
    for (int j = 0; j < 64; ++j){ a += ss[j]; b2 = fmaf(ss[j], cs[j], b2); }
    blkS0[b] = a; blkS0C[b] = b2;
  }
}

// ---- U[b][l]
__global__ void k_u(const unsigned long long* __restrict__ xbits, const float* __restrict__ s0,
                    float* __restrict__ U){
  __shared__ float s0l[64];
  int b = blockIdx.x, l = threadIdx.x;  // 512 threads
  if (l < 64) s0l[l] = s0[b*64 + l];
  __syncthreads();
  unsigned long long w = xbits[(size_t)l*64 + b];
  unsigned int lo = (unsigned)w, hi = (unsigned)(w >> 32);
  unsigned int nlo = ~lo, nhi = ~hi;
  float acc = 0.0f;
  #pragma unroll
  for (int j = 0; j < 32; ++j){
    unsigned int m = (nlo << (31-j)) & 0x80000000u;
    acc += __uint_as_float(__float_as_uint(s0l[j]) ^ m);
  }
  #pragma unroll
  for (int j = 0; j < 32; ++j){
    unsigned int m = (nhi << (31-j)) & 0x80000000u;
    acc += __uint_as_float(__float_as_uint(s0l[32+j]) ^ m);
  }
  U[(size_t)b*512 + l] = acc;
}

// ---- p0
__global__ void k_pinit(const float* __restrict__ llv, const float* __restrict__ s0,
                        float* __restrict__ p0){
  int l = blockIdx.x, lane = threadIdx.x;
  float acc = 0.0f;
  for (int c = 0; c < 64; ++c){
    float v = llv[(size_t)l*4096 + c*64 + lane];
    float sg = (v >= 0.0f) ? 1.0f : -1.0f;
    acc = fmaf(sg, s0[c*64 + lane], acc);
  }
  float tot = wave_allsum(acc);
  if (lane == 0) p0[l] = tot;
}

// ---- chain helpers (r10 verbatim) ----
#define STP(KVAL, J) { \
  int vi_ = __builtin_amdgcn_readlane(__float_as_int(v), (J)); \
  float sg2_ = (vi_ < 0) ? -1.0f : 1.0f; \
  sg_ |= ((unsigned long long)((~((unsigned)vi_)) >> 31)) << (J); \
  v = fmaf(sg2_, (KVAL), v); }
#define STP4(Q, J0) STP(Q.x,(J0)+0) STP(Q.y,(J0)+1) STP(Q.z,(J0)+2) STP(Q.w,(J0)+3)
#define LDK4(P, F0) { P##0 = Kp[((F0)+0)^sw]; P##1 = Kp[((F0)+1)^sw]; \
                      P##2 = Kp[((F0)+2)^sw]; P##3 = Kp[((F0)+3)^sw]; }
#define PROC16(P, J0) STP4(P##0,(J0)) STP4(P##1,(J0)+4) STP4(P##2,(J0)+8) STP4(P##3,(J0)+12)

#define ACC1(F, W, JS) { \
  unsigned int m_ = ((~(W)) << (31-(JS))) & 0x80000000u; \
  acc += __uint_as_float(__float_as_uint(F) ^ m_); }

// ---- the sweep: r10 + async-stage split
__global__ __launch_bounds__(512, 1)
void k_sweep5(const unsigned long long* __restrict__ colbitsP,
              const unsigned long long* __restrict__ xbitsW,
              const float* __restrict__ Kf, const float* __restrict__ baseCorr,
              const float* __restrict__ blkS0, const float* __restrict__ blkS0C,
              const float* __restrict__ U, const float4* __restrict__ cst,
              const float* __restrict__ p0, const float* __restrict__ s0,
              const float* __restrict__ hdr, unsigned long long* __restrict__ sbits)
{
  __shared__ float Kl[2][64][64];                 // 32 KB, f4-swizzled rows
  __shared__ unsigned long long cbl[2][8][64];    // 8 KB
  __shared__ unsigned long long xbl[2][512];      // 8 KB
  __shared__ float Ul[2][512];                    // 4 KB
  __shared__ float4 cstl[2][64];                  // 2 KB
  __shared__ float bcl[2][64];                    // 0.5 KB
  __shared__ float bs0l[64], bscl[64];            // 0.5 KB
  __shared__ float p[512];
  __shared__ float part[8][64];
  __shared__ float red[512];
  __shared__ unsigned long long sig;

  int tid = threadIdx.x, g = tid >> 6, t = tid & 63;
  float rho = hdr[0];

  // prologue: p, P, T + per-block scalars
  p[tid] = p0[tid];
  red[tid] = p0[tid];
  if (tid < 64){ bs0l[tid] = blkS0[tid]; bscl[tid] = blkS0C[tid]; }
  __syncthreads();
  for (int st = 256; st > 0; st >>= 1){ if (tid < st) red[tid] += red[tid+st]; __syncthreads(); }
  float Preg = red[0];
  __syncthreads();
  { float a = 0.0f; for (int k = 0; k < 8; ++k) a += s0[tid*8 + k]; red[tid] = a; }
  __syncthreads();
  for (int st = 256; st > 0; st >>= 1){ if (tid < st) red[tid] += red[tid+st]; __syncthreads(); }
  float Treg = red[0];
  __syncthreads();

  // ---- stage group 0 directly (r10 staging, verbatim) ----
  {
    const float4* Ks = (const float4*)(Kf);
    #pragma unroll
    for (int k = 0; k < 4; ++k){
      int e = tid + k*512;
      float4 vv = Ks[e];
      int gie = e >> 10, row = (e >> 4) & 63, f = e & 15;
      *((float4*)&Kl[gie][row][0] + (f ^ (row & 15))) = vv;
    }
    #pragma unroll
    for (int k = 0; k < 2; ++k){
      int e = tid + k*512;
      int run = e >> 6, tt = e & 63, gie = run >> 3, wl = run & 7;
      cbl[gie][wl][tt] = colbitsP[(size_t)wl*4096 + gie*64 + tt];
    }
    #pragma unroll
    for (int k = 0; k < 2; ++k){
      int e = tid + k*512;
      ((unsigned long long*)xbl)[e] = xbitsW[e];
    }
    #pragma unroll
    for (int k = 0; k < 2; ++k){
      int e = tid + k*512;
      ((float*)Ul)[e] = U[e];
    }
    if (tid < 128){
      ((float4*)cstl)[tid] = cst[tid];
      ((float*)bcl)[tid]   = baseCorr[tid];
    }
  }
  __syncthreads();

  for (int grp = 0; grp < 32; ++grp){
    int ng = grp + 1;
    bool pf = (ng < 32);
    // ---- T14 issue-early: next group's loads into registers ----
    float4 kv0, kv1, kv2, kv3, cstv;
    unsigned long long cbv0, cbv1, xbv0, xbv1;
    float uv0, uv1, bcv;
    if (pf){
      const float4* Ks = (const float4*)(Kf + (size_t)ng*8192);
      kv0 = Ks[tid]; kv1 = Ks[tid+512]; kv2 = Ks[tid+1024]; kv3 = Ks[tid+1536];
      { int e = tid;       int run = e>>6, tt = e&63;
        cbv0 = colbitsP[(size_t)(run&7)*4096 + (ng*2 + (run>>3))*64 + tt]; }
      { int e = tid + 512; int run = e>>6, tt = e&63;
        cbv1 = colbitsP[(size_t)(run&7)*4096 + (ng*2 + (run>>3))*64 + tt]; }
      xbv0 = xbitsW[(size_t)ng*1024 + tid]; xbv1 = xbitsW[(size_t)ng*1024 + tid + 512];
      uv0  = U[(size_t)ng*1024 + tid];      uv1  = U[(size_t)ng*1024 + tid + 512];
      if (tid < 128){ cstv = cst[ng*128 + tid]; bcv = baseCorr[ng*128 + tid]; }
    }

    #pragma unroll
    for (int gi = 0; gi < 2; ++gi){
      int b = grp*2 + gi;
      // ---- phase 1 (r10 verbatim) ----
      {
        unsigned long long w = cbl[gi][g][t];
        unsigned int lo = (unsigned)w, hi = (unsigned)(w >> 32);
        const float4* pw = (const float4*)(p + g*64);
        float acc = 0.0f;
        #pragma unroll
        for (int f = 0; f < 16; ++f){
          float4 q = pw[f];
          if (f < 8){
            ACC1(q.x, lo, 4*f+0) ACC1(q.y, lo, 4*f+1)
            ACC1(q.z, lo, 4*f+2) ACC1(q.w, lo, 4*f+3)
          } else {
            ACC1(q.x, hi, 4*f-32) ACC1(q.y, hi, 4*f-31)
            ACC1(q.z, hi, 4*f-30) ACC1(q.w, hi, 4*f-29)
          }
        }
        part[g][t] = acc;
      }
      __syncthreads();                             // B1

      if (g == 0){
        const float4* Kp = (const float4*)&Kl[gi][t][0];
        int sw = t & 15;
        float4 KA0,KA1,KA2,KA3, KB0,KB1,KB2,KB3;
        LDK4(KA, 0); LDK4(KB, 4);
        float S = 0.0f;
        #pragma unroll
        for (int gg = 0; gg < 8; ++gg) S += part[gg][t];
        float4 cc = cstl[gi][t];
        float bc_ = bcl[gi][t];
        float v = S - cc.x - rho*Preg - cc.y*Treg - bc_;
        unsigned long long sg_ = 0ull;
        PROC16(KA, 0);  LDK4(KA, 8);
        PROC16(KB, 16); LDK4(KB, 12);
        PROC16(KA, 32);
        PROC16(KB, 48);
        if (t == 0){ sig = sg_; sbits[b] = sg_; }
        float sv = ((sg_ >> t) & 1ull) ? cc.w : -cc.w;
        float sc = wave_allsum(sv);
        int pcs = __popcll(sg_);
        Preg += sc - bscl[b];
        Treg += (float)(2*pcs - 64) - bs0l[b];
      }
      __syncthreads();                             // B2
      // ---- phase 3 (r10 verbatim) ----
      {
        unsigned long long sgv = sig;
        int pc = __popcll(xbl[gi][tid] ^ sgv);
        p[tid] = p[tid] + (float)(64 - 2*pc) - Ul[gi][tid];
      }
      __syncthreads();                             // B3
    }

    // ---- T14 write-late: prefetched registers -> LDS, then group barrier ----
    if (pf){
      { int e = tid;        int gie=e>>10, row=(e>>4)&63, f=e&15;
        *((float4*)&Kl[gie][row][0] + (f ^ (row & 15))) = kv0; }
      { int e = tid + 512;  int gie=e>>10, row=(e>>4)&63, f=e&15;
        *((float4*)&Kl[gie][row][0] + (f ^ (row & 15))) = kv1; }
      { int e = tid + 1024; int gie=e>>10, row=(e>>4)&63, f=e&15;
        *((float4*)&Kl[gie][row][0] + (f ^ (row & 15))) = kv2; }
      { int e = tid + 1536; int gie=e>>10, row=(e>>4)&63, f=e&15;
        *((float4*)&Kl[gie][row][0] + (f ^ (row & 15))) = kv3; }
      { int e = tid;       int run=e>>6, tt=e&63; cbl[run>>3][run&7][tt] = cbv0; }
      { int e = tid + 512; int run=e>>6, tt=e&63; cbl[run>>3][run&7][tt] = cbv1; }
      ((unsigned long long*)xbl)[tid]       = xbv0;
      ((unsigned long long*)xbl)[tid + 512] = xbv1;
      ((float*)Ul)[tid]       = uv0;
      ((float*)Ul)[tid + 512] = uv1;
      if (tid < 128){ ((float4*)cstl)[tid] = cstv; ((float*)bcl)[tid] = bcv; }
    }
    __syncthreads();                               // B4 (group boundary)
  }
}

// ---- probe: 128 serially-dependent copies of the exact 64-step chain
__global__ __launch_bounds__(512, 1)
void k_probe(const float* __restrict__ Kf, const float* __restrict__ p0,
             float* __restrict__ scr)
{
  __shared__ float Kl[64][64];
  __shared__ float pv[64];
  int tid = threadIdx.x, g = tid >> 6, t = tid & 63;
  // stage K block 0 (swizzled like the sweep), all 8 waves
  {
    const float4* Ks = (const float4*)(Kf);
    #pragma unroll
    for (int k = 0; k < 2; ++k){
      int e = tid + k*512;
      if (e < 1024){
        float4 vv = Ks[e];
        int row = (e >> 4) & 63, f = e & 15;
        *((float4*)&Kl[row][0] + (f ^ (row & 15))) = vv;
      }
    }
    if (tid < 64) pv[tid] = p0[tid];
  }
  __syncthreads();
  if (g != 0) return;          // waves 1-7 exit; wave0 runs the rep loop

  const float4* Kp = (const float4*)&Kl[t][0];
  int sw = t & 15;
  float v = pv[t];
  unsigned long long chk = 0ull;
  for (int rep = 0; rep < 128; ++rep){
    float4 KA0,KA1,KA2,KA3, KB0,KB1,KB2,KB3;
    LDK4(KA, 0); LDK4(KB, 4);
    unsigned long long sg_ = 0ull;
    PROC16(KA, 0);  LDK4(KA, 8);
    PROC16(KB, 16); LDK4(KB, 12);
    PROC16(KA, 32);
    PROC16(KB, 48);
    chk ^= sg_;
    // serial dependence rep->rep via sg_ (cannot be overlapped or DCE'd)
    v = __int_as_float(__float_as_int(pv[(t + rep) & 63]) ^ ((int)sg_ & 1));
  }
  scr[64 + t] = v;
  if (t == 0) scr[0] = (float)(chk & 0xffffull);
}

// ---- exact integer scores + argmax one-hot
__global__ void k_scores(const unsigned long long* __restrict__ xbits,
                         const unsigned long long* __restrict__ sbits,
                         float* __restrict__ out){
  __shared__ unsigned long long sb[64];
  __shared__ int bestkey;
  int tid = threadIdx.x;  // 512
  if (tid < 64) sb[tid] = sbits[tid];
  if (tid == 0) bestkey = -1;
  __syncthreads();
  int acc = 0;
  #pragma unroll
  for (int w = 0; w < 64; ++w)
    acc += __popcll(xbits[(size_t)tid*64 + w] ^ sb[w]);
  int dot = 4096 - 2*acc;
  int ad  = dot < 0 ? -dot : dot;
  int key = (ad << 10) | (511 - tid);
  atomicMax(&bestkey, key);
  __syncthreads();
  int bl = 511 - (bestkey & 1023);
  float val = (float)(bestkey >> 10) * (1.0f/4096.0f);
  out[tid] = (tid == bl) ? val : 0.0f;
}

extern "C" void kernel_launch(void* const* d_in, const int* in_sizes, int n_in,
                              void* d_out, int out_size, void* d_ws, size_t ws_size,
                              hipStream_t stream){
  const float* s0  = (const float*)d_in[0];   // [4096]
  const float* llv = (const float*)d_in[1];   // [512][4096]
  float* out = (float*)d_out;                 // [512]
  char* ws = (char*)d_ws;

  unsigned long long* colbitsP = (unsigned long long*)(ws + OFF_COLB);
  unsigned long long* xbits    = (unsigned long long*)(ws + OFF_XBITS);
  unsigned long long* xbitsW   = (unsigned long long*)(ws + OFF_XBW);
  float*  Kf    = (float*)(ws + OFF_KF);
  float*  bcorr = (float*)(ws + OFF_BCORR);
  float*  U     = (float*)(ws + OFF_U);
  float4* cst   = (float4*)(ws + OFF_CST);
  float*  p0    = (float*)(ws + OFF_P0);
  unsigned long long* sbits = (unsigned long long*)(ws + OFF_SBITS);
  int*    colcnt = (int*)(ws + OFF_CNT);
  float*  hdr   = (float*)(ws + OFF_HDR);
  float*  bS0   = (float*)(ws + OFF_BS0);
  float*  bS0C  = (float*)(ws + OFF_BS0C);
  float*  scr   = (float*)(ws + OFF_SCR);

  k_xbits<<<128, 256, 0, stream>>>(llv, xbits, xbitsW);
  k_bitT<<<dim3(8, 64), 64, 0, stream>>>(xbits, colbitsP);
  k_colc<<<16, 256, 0, stream>>>(colbitsP, colcnt);
  k_rho<<<1, 256, 0, stream>>>(colcnt, hdr);
  k_const<<<16, 256, 0, stream>>>(colcnt, hdr, s0, cst);
  k_kdiag<<<64, 256, 0, stream>>>(colbitsP, cst, s0, hdr, Kf, bcorr, bS0, bS0C);
  k_u<<<64, 512, 0, stream>>>(xbits, s0, U);
  k_pinit<<<512, 64, 0, stream>>>(llv, s0, p0);
  k_sweep5<<<1, 512, 0, stream>>>(colbitsP, xbitsW, Kf, bcorr, bS0, bS0C, U, cst, p0, s0, hdr, sbits);
  k_scores<<<1, 512, 0, stream>>>(xbits, sbits, out);
  k_probe<<<1, 512, 0, stream>>>(Kf, p0, scr);   // measurement only (ws scratch)
}

// Round 13
// 240.537 us; speedup vs baseline: 1.6219x; 1.6219x over previous
//
#include <hip/hip_runtime.h>
#include <hip/hip_bf16.h>

// Hopfield forward, blocked factored Gauss-Seidel.
// Round 13: chain rewritten as group-of-4 batched-readlane resolve (bit-exact
// vs r10/r12: same add order; K^signmask == fmaf(+-1,K,v)). B3 removed
// (p is wave-local; part/sig protected by B1/B2). Probe removed.

#define OFF_COLB   0u                       // u64 [8][4096]  colbitsP
#define OFF_XBITS  (256u<<10)               // u64 [512][64]  row bits
#define OFF_XBW    (512u<<10)               // u64 [64][512]  xbitsW
#define OFF_KF     (768u<<10)               // f32 [64][64][64] Kdiag : 1 MB
#define OFF_BCORR  (1792u<<10)              // f32 [4096] baseCorr
#define OFF_U      (1808u<<10)              // f32 [64][512] U
#define OFF_CST    (1936u<<10)              // float4 [4096]
#define OFF_P0     (2000u<<10)              // f32 [512]
#define OFF_SBITS  (2002u<<10)              // u64 [64]
#define OFF_CNT    (2003u<<10)              // int [4096]
#define OFF_HDR    (2019u<<10)              // f32 [16]
#define OFF_BS0    (2020u<<10)              // f32 [64]
#define OFF_BS0C   (2021u<<10)              // f32 [64]

template<int CTRL, int RMASK>
__device__ __forceinline__ float dpp_add(float x){
  int t = __builtin_amdgcn_update_dpp(0, __float_as_int(x), CTRL, RMASK, 0xf, true);
  return x + __int_as_float(t);
}
__device__ __forceinline__ float wave_allsum(float x){
  x = dpp_add<0x111,0xf>(x);
  x = dpp_add<0x112,0xf>(x);
  x = dpp_add<0x114,0xf>(x);
  x = dpp_add<0x118,0xf>(x);
  x = dpp_add<0x142,0xa>(x);
  x = dpp_add<0x143,0xc>(x);
  return __int_as_float(__builtin_amdgcn_readlane(__float_as_int(x), 63));
}

// ---- row bits + transposed-block layout
__global__ void k_xbits(const float* __restrict__ llv, unsigned long long* __restrict__ xbits,
                        unsigned long long* __restrict__ xbitsW){
  int w = threadIdx.x >> 6, lane = threadIdx.x & 63;
  int l = blockIdx.x*4 + w;
  unsigned long long myword = 0;
  for (int c = 0; c < 64; ++c){
    float v = llv[(size_t)l*4096 + c*64 + lane];
    unsigned long long b = __ballot(v >= 0.0f);
    if (c == lane) myword = b;
  }
  xbits[(size_t)l*64 + lane] = myword;
  xbitsW[(size_t)lane*512 + l] = myword;
}

// ---- bit transpose
__global__ void k_bitT(const unsigned long long* __restrict__ xbits,
                       unsigned long long* __restrict__ colbitsP){
  int li = blockIdx.x, ii = blockIdx.y, lane = threadIdx.x;
  unsigned long long w = xbits[(size_t)(li*64 + lane)*64 + ii];
  unsigned long long myw = 0;
  for (int j = 0; j < 64; ++j){
    unsigned long long b = __ballot((w >> j) & 1ull);
    if (j == lane) myw = b;
  }
  colbitsP[(size_t)li*4096 + ii*64 + lane] = myw;
}

// ---- column positive counts
__global__ void k_colc(const unsigned long long* __restrict__ colbitsP, int* __restrict__ colcnt){
  int i = blockIdx.x*256 + threadIdx.x;
  int c = 0;
  #pragma unroll
  for (int wl = 0; wl < 8; ++wl) c += __popcll(colbitsP[(size_t)wl*4096 + i]);
  colcnt[i] = c;
}

// ---- rho
__global__ void k_rho(const int* __restrict__ colcnt, float* __restrict__ hdr){
  __shared__ int sh[256];
  int tid = threadIdx.x;
  int s = 0;
  for (int k = tid; k < 4096; k += 256) s += colcnt[k];
  sh[tid] = s; __syncthreads();
  for (int st = 128; st > 0; st >>= 1){
    if (tid < st) sh[tid] += sh[tid + st];
    __syncthreads();
  }
  if (tid == 0){
    int num = 2*sh[0] - 2097152;
    hdr[0] = (float)num * (1.0f/2097152.0f);
  }
}

// ---- per-step constants
__global__ void k_const(const int* __restrict__ colcnt, const float* __restrict__ hdr,
                        const float* __restrict__ s0, float4* __restrict__ cst){
  int i = blockIdx.x*256 + threadIdx.x;
  float rho = hdr[0];
  float c  = (float)(2*colcnt[i] - 512);
  float r2 = rho*rho;
  float q  = 512.0f + 512.0f*r2 - 2.0f*rho*c;
  float s  = s0[i];
  float4 o;
  o.x = q * s;
  o.y = rho*c - 512.0f*r2;
  o.z = 1.0f - s;
  o.w = c;
  cst[i] = o;
}

// ---- diagonal K blocks + baseCorr + block s0 sums
__global__ void k_kdiag(const unsigned long long* __restrict__ colbitsP,
                        const float4* __restrict__ cst, const float* __restrict__ s0,
                        const float* __restrict__ hdr,
                        float* __restrict__ Kf, float* __restrict__ baseCorr,
                        float* __restrict__ blkS0, float* __restrict__ blkS0C){
  __shared__ unsigned long long cb[8][64];
  __shared__ float Kl[64][64];
  __shared__ float cs[64], ss[64];
  int b = blockIdx.x, i0 = b*64, tid = threadIdx.x;  // 256 threads
  for (int k = tid; k < 512; k += 256)
    cb[k>>6][k&63] = colbitsP[(size_t)(k>>6)*4096 + i0 + (k&63)];
  if (tid < 64){ cs[tid] = cst[i0+tid].w; ss[tid] = s0[i0+tid]; }
  __syncthreads();
  float rho = hdr[0];
  float r2t = 512.0f*rho*rho;
  #pragma unroll
  for (int k = 0; k < 16; ++k){
    int q = tid*16 + k;
    int t = q >> 6, j = q & 63;
    int acc = 0;
    #pragma unroll
    for (int wl = 0; wl < 8; ++wl) acc += __popcll(cb[wl][t] ^ cb[wl][j]);
    float G = (float)(512 - 2*acc);
    float kf = G - rho*(cs[t]+cs[j]) + r2t;
    Kl[t][j] = kf;
    Kf[(size_t)b*4096 + q] = kf;
  }
  __syncthreads();
  if (tid < 64){
    float bc = 0.0f;
    for (int j = 0; j < tid; ++j) bc = fmaf(ss[j], Kl[tid][j], bc);
    baseCorr[i0 + tid] = bc;
  }
  if (tid == 64){
    float a = 0.0f, b2 = 0.0f;
    for (int j = 0; j < 64; ++j){ a += ss[j]; b2 = fmaf(ss[j], cs[j], b2); }
    blkS0[b] = a; blkS0C[b] = b2;
  }
}

// ---- U[b][l]
__global__ void k_u(const unsigned long long* __restrict__ xbits, const float* __restrict__ s0,
                    float* __restrict__ U){
  __shared__ float s0l[64];
  int b = blockIdx.x, l = threadIdx.x;  // 512 threads
  if (l < 64) s0l[l] = s0[b*64 + l];
  __syncthreads();
  unsigned long long w = xbits[(size_t)l*64 + b];
  unsigned int lo = (unsigned)w, hi = (unsigned)(w >> 32);
  unsigned int nlo = ~lo, nhi = ~hi;
  float acc = 0.0f;
  #pragma unroll
  for (int j = 0; j < 32; ++j){
    unsigned int m = (nlo << (31-j)) & 0x80000000u;
    acc += __uint_as_float(__float_as_uint(s0l[j]) ^ m);
  }
  #pragma unroll
  for (int j = 0; j < 32; ++j){
    unsigned int m = (nhi << (31-j)) & 0x80000000u;
    acc += __uint_as_float(__float_as_uint(s0l[32+j]) ^ m);
  }
  U[(size_t)b*512 + l] = acc;
}

// ---- p0
__global__ void k_pinit(const float* __restrict__ llv, const float* __restrict__ s0,
                        float* __restrict__ p0){
  int l = blockIdx.x, lane = threadIdx.x;
  float acc = 0.0f;
  for (int c = 0; c < 64; ++c){
    float v = llv[(size_t)l*4096 + c*64 + lane];
    float sg = (v >= 0.0f) ? 1.0f : -1.0f;
    acc = fmaf(sg, s0[c*64 + lane], acc);
  }
  float tot = wave_allsum(acc);
  if (lane == 0) p0[l] = tot;
}

// ---- phase-1 accumulate helper
#define ACC1(F, W, JS) { \
  unsigned int m_ = ((~(W)) << (31-(JS))) & 0x80000000u; \
  acc += __uint_as_float(__float_as_uint(F) ^ m_); }

// ---- group-of-4 batched-readlane resolve (bit-exact vs serial chain) ----
#define KRL(X, L) __builtin_amdgcn_readlane(__float_as_int(X), (L))
#define GRP4(CQ, Qi) { \
  int k10_ = KRL(CQ.x, 4*(Qi)+1); \
  int k20_ = KRL(CQ.x, 4*(Qi)+2); \
  int k30_ = KRL(CQ.x, 4*(Qi)+3); \
  int k21_ = KRL(CQ.y, 4*(Qi)+2); \
  int k31_ = KRL(CQ.y, 4*(Qi)+3); \
  int k32_ = KRL(CQ.z, 4*(Qi)+3); \
  int w0_ = KRL(v, 4*(Qi)+0); \
  int w1_ = KRL(v, 4*(Qi)+1); \
  int w2_ = KRL(v, 4*(Qi)+2); \
  int w3_ = KRL(v, 4*(Qi)+3); \
  unsigned s0_ = ((unsigned)w0_) & 0x80000000u; \
  float u1_ = __int_as_float(w1_) + __uint_as_float(((unsigned)k10_) ^ s0_); \
  unsigned s1_ = __float_as_uint(u1_) & 0x80000000u; \
  float u2_ = (__int_as_float(w2_) + __uint_as_float(((unsigned)k20_) ^ s0_)) \
            + __uint_as_float(((unsigned)k21_) ^ s1_); \
  unsigned s2_ = __float_as_uint(u2_) & 0x80000000u; \
  float u3_ = ((__int_as_float(w3_) + __uint_as_float(((unsigned)k30_) ^ s0_)) \
            + __uint_as_float(((unsigned)k31_) ^ s1_)) \
            + __uint_as_float(((unsigned)k32_) ^ s2_); \
  unsigned s3_ = __float_as_uint(u3_) & 0x80000000u; \
  sg_ |= ((unsigned long long)(1u ^ (s0_ >> 31))) << (4*(Qi)+0); \
  sg_ |= ((unsigned long long)(1u ^ (s1_ >> 31))) << (4*(Qi)+1); \
  sg_ |= ((unsigned long long)(1u ^ (s2_ >> 31))) << (4*(Qi)+2); \
  sg_ |= ((unsigned long long)(1u ^ (s3_ >> 31))) << (4*(Qi)+3); \
  v = v + __uint_as_float(__float_as_uint(CQ.x) ^ s0_); \
  v = v + __uint_as_float(__float_as_uint(CQ.y) ^ s1_); \
  v = v + __uint_as_float(__float_as_uint(CQ.z) ^ s2_); \
  v = v + __uint_as_float(__float_as_uint(CQ.w) ^ s3_); \
}

// ---- the sweep: LDS-resident + T14 async-stage + batched-resolve chain
__global__ __launch_bounds__(512, 1)
void k_sweep6(const unsigned long long* __restrict__ colbitsP,
              const unsigned long long* __restrict__ xbitsW,
              const float* __restrict__ Kf, const float* __restrict__ baseCorr,
              const float* __restrict__ blkS0, const float* __restrict__ blkS0C,
              const float* __restrict__ U, const float4* __restrict__ cst,
              const float* __restrict__ p0, const float* __restrict__ s0,
              const float* __restrict__ hdr, unsigned long long* __restrict__ sbits)
{
  __shared__ float Kl[2][64][64];                 // 32 KB, f4-swizzled rows
  __shared__ unsigned long long cbl[2][8][64];    // 8 KB
  __shared__ unsigned long long xbl[2][512];      // 8 KB
  __shared__ float Ul[2][512];                    // 4 KB
  __shared__ float4 cstl[2][64];                  // 2 KB
  __shared__ float bcl[2][64];                    // 0.5 KB
  __shared__ float bs0l[64], bscl[64];            // 0.5 KB
  __shared__ float p[512];
  __shared__ float part[8][64];
  __shared__ float red[512];
  __shared__ unsigned long long sig;

  int tid = threadIdx.x, g = tid >> 6, t = tid & 63;
  float rho = hdr[0];

  // prologue: p, P, T + per-block scalars
  p[tid] = p0[tid];
  red[tid] = p0[tid];
  if (tid < 64){ bs0l[tid] = blkS0[tid]; bscl[tid] = blkS0C[tid]; }
  __syncthreads();
  for (int st = 256; st > 0; st >>= 1){ if (tid < st) red[tid] += red[tid+st]; __syncthreads(); }
  float Preg = red[0];
  __syncthreads();
  { float a = 0.0f; for (int k = 0; k < 8; ++k) a += s0[tid*8 + k]; red[tid] = a; }
  __syncthreads();
  for (int st = 256; st > 0; st >>= 1){ if (tid < st) red[tid] += red[tid+st]; __syncthreads(); }
  float Treg = red[0];
  __syncthreads();

  // ---- stage group 0 directly ----
  {
    const float4* Ks = (const float4*)(Kf);
    #pragma unroll
    for (int k = 0; k < 4; ++k){
      int e = tid + k*512;
      float4 vv = Ks[e];
      int gie = e >> 10, row = (e >> 4) & 63, f = e & 15;
      *((float4*)&Kl[gie][row][0] + (f ^ (row & 15))) = vv;
    }
    #pragma unroll
    for (int k = 0; k < 2; ++k){
      int e = tid + k*512;
      int run = e >> 6, tt = e & 63, gie = run >> 3, wl = run & 7;
      cbl[gie][wl][tt] = colbitsP[(size_t)wl*4096 + gie*64 + tt];
    }
    #pragma unroll
    for (int k = 0; k < 2; ++k){
      int e = tid + k*512;
      ((unsigned long long*)xbl)[e] = xbitsW[e];
    }
    #pragma unroll
    for (int k = 0; k < 2; ++k){
      int e = tid + k*512;
      ((float*)Ul)[e] = U[e];
    }
    if (tid < 128){
      ((float4*)cstl)[tid] = cst[tid];
      ((float*)bcl)[tid]   = baseCorr[tid];
    }
  }
  __syncthreads();

  for (int grp = 0; grp < 32; ++grp){
    int ng = grp + 1;
    bool pf = (ng < 32);
    // ---- T14 issue-early: next group's loads into registers ----
    float4 kv0, kv1, kv2, kv3, cstv;
    unsigned long long cbv0, cbv1, xbv0, xbv1;
    float uv0, uv1, bcv;
    if (pf){
      const float4* Ks = (const float4*)(Kf + (size_t)ng*8192);
      kv0 = Ks[tid]; kv1 = Ks[tid+512]; kv2 = Ks[tid+1024]; kv3 = Ks[tid+1536];
      { int e = tid;       int run = e>>6, tt = e&63;
        cbv0 = colbitsP[(size_t)(run&7)*4096 + (ng*2 + (run>>3))*64 + tt]; }
      { int e = tid + 512; int run = e>>6, tt = e&63;
        cbv1 = colbitsP[(size_t)(run&7)*4096 + (ng*2 + (run>>3))*64 + tt]; }
      xbv0 = xbitsW[(size_t)ng*1024 + tid]; xbv1 = xbitsW[(size_t)ng*1024 + tid + 512];
      uv0  = U[(size_t)ng*1024 + tid];      uv1  = U[(size_t)ng*1024 + tid + 512];
      if (tid < 128){ cstv = cst[ng*128 + tid]; bcv = baseCorr[ng*128 + tid]; }
    }

    #pragma unroll
    for (int gi = 0; gi < 2; ++gi){
      int b = grp*2 + gi;
      // ---- phase 1 ----
      {
        unsigned long long w = cbl[gi][g][t];
        unsigned int lo = (unsigned)w, hi = (unsigned)(w >> 32);
        const float4* pw = (const float4*)(p + g*64);
        float acc = 0.0f;
        #pragma unroll
        for (int f = 0; f < 16; ++f){
          float4 q = pw[f];
          if (f < 8){
            ACC1(q.x, lo, 4*f+0) ACC1(q.y, lo, 4*f+1)
            ACC1(q.z, lo, 4*f+2) ACC1(q.w, lo, 4*f+3)
          } else {
            ACC1(q.x, hi, 4*f-32) ACC1(q.y, hi, 4*f-31)
            ACC1(q.z, hi, 4*f-30) ACC1(q.w, hi, 4*f-29)
          }
        }
        part[g][t] = acc;
      }
      __syncthreads();                             // B1

      if (g == 0){
        const float4* Kp = (const float4*)&Kl[gi][t][0];
        int sw = t & 15;
        float S = 0.0f;
        #pragma unroll
        for (int gg = 0; gg < 8; ++gg) S += part[gg][t];
        float4 cc = cstl[gi][t];
        float bc_ = bcl[gi][t];
        float v = S - cc.x - rho*Preg - cc.y*Treg - bc_;
        float4 C0 = Kp[0^sw], C1 = Kp[1^sw], C2 = Kp[2^sw];
        unsigned long long sg_ = 0ull;
        GRP4(C0, 0);  C0 = Kp[3^sw];
        GRP4(C1, 1);  C1 = Kp[4^sw];
        GRP4(C2, 2);  C2 = Kp[5^sw];
        GRP4(C0, 3);  C0 = Kp[6^sw];
        GRP4(C1, 4);  C1 = Kp[7^sw];
        GRP4(C2, 5);  C2 = Kp[8^sw];
        GRP4(C0, 6);  C0 = Kp[9^sw];
        GRP4(C1, 7);  C1 = Kp[10^sw];
        GRP4(C2, 8);  C2 = Kp[11^sw];
        GRP4(C0, 9);  C0 = Kp[12^sw];
        GRP4(C1, 10); C1 = Kp[13^sw];
        GRP4(C2, 11); C2 = Kp[14^sw];
        GRP4(C0, 12); C0 = Kp[15^sw];
        GRP4(C1, 13);
        GRP4(C2, 14);
        GRP4(C0, 15);
        if (t == 0){ sig = sg_; sbits[b] = sg_; }
        float sv = ((sg_ >> t) & 1ull) ? cc.w : -cc.w;
        float sc = wave_allsum(sv);
        int pcs = __popcll(sg_);
        Preg += sc - bscl[b];
        Treg += (float)(2*pcs - 64) - bs0l[b];
      }
      __syncthreads();                             // B2
      // ---- phase 3 (no B3 after: p is wave-local, part/sig guarded by B1/B2) ----
      {
        unsigned long long sgv = sig;
        int pc = __popcll(xbl[gi][tid] ^ sgv);
        p[tid] = p[tid] + (float)(64 - 2*pc) - Ul[gi][tid];
      }
    }

    // ---- T14 write-late: prefetched registers -> LDS, then group barrier ----
    if (pf){
      { int e = tid;        int gie=e>>10, row=(e>>4)&63, f=e&15;
        *((float4*)&Kl[gie][row][0] + (f ^ (row & 15))) = kv0; }
      { int e = tid + 512;  int gie=e>>10, row=(e>>4)&63, f=e&15;
        *((float4*)&Kl[gie][row][0] + (f ^ (row & 15))) = kv1; }
      { int e = tid + 1024; int gie=e>>10, row=(e>>4)&63, f=e&15;
        *((float4*)&Kl[gie][row][0] + (f ^ (row & 15))) = kv2; }
      { int e = tid + 1536; int gie=e>>10, row=(e>>4)&63, f=e&15;
        *((float4*)&Kl[gie][row][0] + (f ^ (row & 15))) = kv3; }
      { int e = tid;       int run=e>>6, tt=e&63; cbl[run>>3][run&7][tt] = cbv0; }
      { int e = tid + 512; int run=e>>6, tt=e&63; cbl[run>>3][run&7][tt] = cbv1; }
      ((unsigned long long*)xbl)[tid]       = xbv0;
      ((unsigned long long*)xbl)[tid + 512] = xbv1;
      ((float*)Ul)[tid]       = uv0;
      ((float*)Ul)[tid + 512] = uv1;
      if (tid < 128){ ((float4*)cstl)[tid] = cstv; ((float*)bcl)[tid] = bcv; }
    }
    __syncthreads();                               // B4 (group boundary)
  }
}

// ---- exact integer scores + argmax one-hot
__global__ void k_scores(const unsigned long long* __restrict__ xbits,
                         const unsigned long long* __restrict__ sbits,
                         float* __restrict__ out){
  __shared__ unsigned long long sb[64];
  __shared__ int bestkey;
  int tid = threadIdx.x;  // 512
  if (tid < 64) sb[tid] = sbits[tid];
  if (tid == 0) bestkey = -1;
  __syncthreads();
  int acc = 0;
  #pragma unroll
  for (int w = 0; w < 64; ++w)
    acc += __popcll(xbits[(size_t)tid*64 + w] ^ sb[w]);
  int dot = 4096 - 2*acc;
  int ad  = dot < 0 ? -dot : dot;
  int key = (ad << 10) | (511 - tid);
  atomicMax(&bestkey, key);
  __syncthreads();
  int bl = 511 - (bestkey & 1023);
  float val = (float)(bestkey >> 10) * (1.0f/4096.0f);
  out[tid] = (tid == bl) ? val : 0.0f;
}

extern "C" void kernel_launch(void* const* d_in, const int* in_sizes, int n_in,
                              void* d_out, int out_size, void* d_ws, size_t ws_size,
                              hipStream_t stream){
  const float* s0  = (const float*)d_in[0];   // [4096]
  const float* llv = (const float*)d_in[1];   // [512][4096]
  float* out = (float*)d_out;                 // [512]
  char* ws = (char*)d_ws;

  unsigned long long* colbitsP = (unsigned long long*)(ws + OFF_COLB);
  unsigned long long* xbits    = (unsigned long long*)(ws + OFF_XBITS);
  unsigned long long* xbitsW   = (unsigned long long*)(ws + OFF_XBW);
  float*  Kf    = (float*)(ws + OFF_KF);
  float*  bcorr = (float*)(ws + OFF_BCORR);
  float*  U     = (float*)(ws + OFF_U);
  float4* cst   = (float4*)(ws + OFF_CST);
  float*  p0    = (float*)(ws + OFF_P0);
  unsigned long long* sbits = (unsigned long long*)(ws + OFF_SBITS);
  int*    colcnt = (int*)(ws + OFF_CNT);
  float*  hdr   = (float*)(ws + OFF_HDR);
  float*  bS0   = (float*)(ws + OFF_BS0);
  float*  bS0C  = (float*)(ws + OFF_BS0C);

  k_xbits<<<128, 256, 0, stream>>>(llv, xbits, xbitsW);
  k_bitT<<<dim3(8, 64), 64, 0, stream>>>(xbits, colbitsP);
  k_colc<<<16, 256, 0, stream>>>(colbitsP, colcnt);
  k_rho<<<1, 256, 0, stream>>>(colcnt, hdr);
  k_const<<<16, 256, 0, stream>>>(colcnt, hdr, s0, cst);
  k_kdiag<<<64, 256, 0, stream>>>(colbitsP, cst, s0, hdr, Kf, bcorr, bS0, bS0C);
  k_u<<<64, 512, 0, stream>>>(xbits, s0, U);
  k_pinit<<<512, 64, 0, stream>>>(llv, s0, p0);
  k_sweep6<<<1, 512, 0, stream>>>(colbitsP, xbitsW, Kf, bcorr, bS0, bS0C, U, cst, p0, s0, hdr, sbits);
  k_scores<<<1, 512, 0, stream>>>(xbits, sbits, out);
}

// Round 14
// 210.820 us; speedup vs baseline: 1.8505x; 1.1410x over previous
//
#include <hip/hip_runtime.h>
#include <hip/hip_bf16.h>

// Hopfield forward, blocked factored Gauss-Seidel.
// Round 14: ballot chain — per-step sign broadcast via __ballot (uniform SGPR),
// zero readlanes. Bit-identical to the passing serial chain (int-sign compare;
// v+(K^mask) == fmaf(+-1,K,v); same add order). Rest identical to r13
// (LDS-resident groups, T14 async-stage, no B3).

#define OFF_COLB   0u                       // u64 [8][4096]  colbitsP
#define OFF_XBITS  (256u<<10)               // u64 [512][64]  row bits
#define OFF_XBW    (512u<<10)               // u64 [64][512]  xbitsW
#define OFF_KF     (768u<<10)               // f32 [64][64][64] Kdiag : 1 MB
#define OFF_BCORR  (1792u<<10)              // f32 [4096] baseCorr
#define OFF_U      (1808u<<10)              // f32 [64][512] U
#define OFF_CST    (1936u<<10)              // float4 [4096]
#define OFF_P0     (2000u<<10)              // f32 [512]
#define OFF_SBITS  (2002u<<10)              // u64 [64]
#define OFF_CNT    (2003u<<10)              // int [4096]
#define OFF_HDR    (2019u<<10)              // f32 [16]
#define OFF_BS0    (2020u<<10)              // f32 [64]
#define OFF_BS0C   (2021u<<10)              // f32 [64]

template<int CTRL, int RMASK>
__device__ __forceinline__ float dpp_add(float x){
  int t = __builtin_amdgcn_update_dpp(0, __float_as_int(x), CTRL, RMASK, 0xf, true);
  return x + __int_as_float(t);
}
__device__ __forceinline__ float wave_allsum(float x){
  x = dpp_add<0x111,0xf>(x);
  x = dpp_add<0x112,0xf>(x);
  x = dpp_add<0x114,0xf>(x);
  x = dpp_add<0x118,0xf>(x);
  x = dpp_add<0x142,0xa>(x);
  x = dpp_add<0x143,0xc>(x);
  return __int_as_float(__builtin_amdgcn_readlane(__float_as_int(x), 63));
}

// ---- row bits + transposed-block layout
__global__ void k_xbits(const float* __restrict__ llv, unsigned long long* __restrict__ xbits,
                        unsigned long long* __restrict__ xbitsW){
  int w = threadIdx.x >> 6, lane = threadIdx.x & 63;
  int l = blockIdx.x*4 + w;
  unsigned long long myword = 0;
  for (int c = 0; c < 64; ++c){
    float v = llv[(size_t)l*4096 + c*64 + lane];
    unsigned long long b = __ballot(v >= 0.0f);
    if (c == lane) myword = b;
  }
  xbits[(size_t)l*64 + lane] = myword;
  xbitsW[(size_t)lane*512 + l] = myword;
}

// ---- bit transpose
__global__ void k_bitT(const unsigned long long* __restrict__ xbits,
                       unsigned long long* __restrict__ colbitsP){
  int li = blockIdx.x, ii = blockIdx.y, lane = threadIdx.x;
  unsigned long long w = xbits[(size_t)(li*64 + lane)*64 + ii];
  unsigned long long myw = 0;
  for (int j = 0; j < 64; ++j){
    unsigned long long b = __ballot((w >> j) & 1ull);
    if (j == lane) myw = b;
  }
  colbitsP[(size_t)li*4096 + ii*64 + lane] = myw;
}

// ---- column positive counts
__global__ void k_colc(const unsigned long long* __restrict__ colbitsP, int* __restrict__ colcnt){
  int i = blockIdx.x*256 + threadIdx.x;
  int c = 0;
  #pragma unroll
  for (int wl = 0; wl < 8; ++wl) c += __popcll(colbitsP[(size_t)wl*4096 + i]);
  colcnt[i] = c;
}

// ---- rho
__global__ void k_rho(const int* __restrict__ colcnt, float* __restrict__ hdr){
  __shared__ int sh[256];
  int tid = threadIdx.x;
  int s = 0;
  for (int k = tid; k < 4096; k += 256) s += colcnt[k];
  sh[tid] = s; __syncthreads();
  for (int st = 128; st > 0; st >>= 1){
    if (tid < st) sh[tid] += sh[tid + st];
    __syncthreads();
  }
  if (tid == 0){
    int num = 2*sh[0] - 2097152;
    hdr[0] = (float)num * (1.0f/2097152.0f);
  }
}

// ---- per-step constants
__global__ void k_const(const int* __restrict__ colcnt, const float* __restrict__ hdr,
                        const float* __restrict__ s0, float4* __restrict__ cst){
  int i = blockIdx.x*256 + threadIdx.x;
  float rho = hdr[0];
  float c  = (float)(2*colcnt[i] - 512);
  float r2 = rho*rho;
  float q  = 512.0f + 512.0f*r2 - 2.0f*rho*c;
  float s  = s0[i];
  float4 o;
  o.x = q * s;
  o.y = rho*c - 512.0f*r2;
  o.z = 1.0f - s;
  o.w = c;
  cst[i] = o;
}

// ---- diagonal K blocks + baseCorr + block s0 sums
__global__ void k_kdiag(const unsigned long long* __restrict__ colbitsP,
                        const float4* __restrict__ cst, const float* __restrict__ s0,
                        const float* __restrict__ hdr,
                        float* __restrict__ Kf, float* __restrict__ baseCorr,
                        float* __restrict__ blkS0, float* __restrict__ blkS0C){
  __shared__ unsigned long long cb[8][64];
  __shared__ float Kl[64][64];
  __shared__ float cs[64], ss[64];
  int b = blockIdx.x, i0 = b*64, tid = threadIdx.x;  // 256 threads
  for (int k = tid; k < 512; k += 256)
    cb[k>>6][k&63] = colbitsP[(size_t)(k>>6)*4096 + i0 + (k&63)];
  if (tid < 64){ cs[tid] = cst[i0+tid].w; ss[tid] = s0[i0+tid]; }
  __syncthreads();
  float rho = hdr[0];
  float r2t = 512.0f*rho*rho;
  #pragma unroll
  for (int k = 0; k < 16; ++k){
    int q = tid*16 + k;
    int t = q >> 6, j = q & 63;
    int acc = 0;
    #pragma unroll
    for (int wl = 0; wl < 8; ++wl) acc += __popcll(cb[wl][t] ^ cb[wl][j]);
    float G = (float)(512 - 2*acc);
    float kf = G - rho*(cs[t]+cs[j]) + r2t;
    Kl[t][j] = kf;
    Kf[(size_t)b*4096 + q] = kf;
  }
  __syncthreads();
  if (tid < 64){
    float bc = 0.0f;
    for (int j = 0; j < tid; ++j) bc = fmaf(ss[j], Kl[tid][j], bc);
    baseCorr[i0 + tid] = bc;
  }
  if (tid == 64){
    float a = 0.0f, b2 = 0.0f;
    for (int j = 0; j < 64; ++j){ a += ss[j]; b2 = fmaf(ss[j], cs[j], b2); }
    blkS0[b] = a; blkS0C[b] = b2;
  }
}

// ---- U[b][l]
__global__ void k_u(const unsigned long long* __restrict__ xbits, const float* __restrict__ s0,
                    float* __restrict__ U){
  __shared__ float s0l[64];
  int b = blockIdx.x, l = threadIdx.x;  // 512 threads
  if (l < 64) s0l[l] = s0[b*64 + l];
  __syncthreads();
  unsigned long long w = xbits[(size_t)l*64 + b];
  unsigned int lo = (unsigned)w, hi = (unsigned)(w >> 32);
  unsigned int nlo = ~lo, nhi = ~hi;
  float acc = 0.0f;
  #pragma unroll
  for (int j = 0; j < 32; ++j){
    unsigned int m = (nlo << (31-j)) & 0x80000000u;
    acc += __uint_as_float(__float_as_uint(s0l[j]) ^ m);
  }
  #pragma unroll
  for (int j = 0; j < 32; ++j){
    unsigned int m = (nhi << (31-j)) & 0x80000000u;
    acc += __uint_as_float(__float_as_uint(s0l[32+j]) ^ m);
  }
  U[(size_t)b*512 + l] = acc;
}

// ---- p0
__global__ void k_pinit(const float* __restrict__ llv, const float* __restrict__ s0,
                        float* __restrict__ p0){
  int l = blockIdx.x, lane = threadIdx.x;
  float acc = 0.0f;
  for (int c = 0; c < 64; ++c){
    float v = llv[(size_t)l*4096 + c*64 + lane];
    float sg = (v >= 0.0f) ? 1.0f : -1.0f;
    acc = fmaf(sg, s0[c*64 + lane], acc);
  }
  float tot = wave_allsum(acc);
  if (lane == 0) p0[l] = tot;
}

// ---- phase-1 accumulate helper
#define ACC1(F, W, JS) { \
  unsigned int m_ = ((~(W)) << (31-(JS))) & 0x80000000u; \
  acc += __uint_as_float(__float_as_uint(F) ^ m_); }

// ---- ballot chain step: sign broadcast via __ballot (uniform SGPR), no readlane.
// Bit-identical to serial STP: int-sign compare; v+(K^mask) == fmaf(+-1,K,v).
#define BSTP(KVAL, J) { \
  unsigned long long neg_ = __ballot(__float_as_int(v) < 0); \
  unsigned b_ = (unsigned)(neg_ >> (J)) & 1u; \
  sg_ |= ((unsigned long long)(b_ ^ 1u)) << (J); \
  v = v + __uint_as_float(__float_as_uint(KVAL) ^ (b_ << 31)); }
#define BST4(Q, J0) BSTP(Q.x,(J0)+0) BSTP(Q.y,(J0)+1) BSTP(Q.z,(J0)+2) BSTP(Q.w,(J0)+3)

// ---- the sweep: LDS-resident + T14 async-stage + ballot chain
__global__ __launch_bounds__(512, 1)
void k_sweep6(const unsigned long long* __restrict__ colbitsP,
              const unsigned long long* __restrict__ xbitsW,
              const float* __restrict__ Kf, const float* __restrict__ baseCorr,
              const float* __restrict__ blkS0, const float* __restrict__ blkS0C,
              const float* __restrict__ U, const float4* __restrict__ cst,
              const float* __restrict__ p0, const float* __restrict__ s0,
              const float* __restrict__ hdr, unsigned long long* __restrict__ sbits)
{
  __shared__ float Kl[2][64][64];                 // 32 KB, f4-swizzled rows
  __shared__ unsigned long long cbl[2][8][64];    // 8 KB
  __shared__ unsigned long long xbl[2][512];      // 8 KB
  __shared__ float Ul[2][512];                    // 4 KB
  __shared__ float4 cstl[2][64];                  // 2 KB
  __shared__ float bcl[2][64];                    // 0.5 KB
  __shared__ float bs0l[64], bscl[64];            // 0.5 KB
  __shared__ float p[512];
  __shared__ float part[8][64];
  __shared__ float red[512];
  __shared__ unsigned long long sig;

  int tid = threadIdx.x, g = tid >> 6, t = tid & 63;
  float rho = hdr[0];

  // prologue: p, P, T + per-block scalars
  p[tid] = p0[tid];
  red[tid] = p0[tid];
  if (tid < 64){ bs0l[tid] = blkS0[tid]; bscl[tid] = blkS0C[tid]; }
  __syncthreads();
  for (int st = 256; st > 0; st >>= 1){ if (tid < st) red[tid] += red[tid+st]; __syncthreads(); }
  float Preg = red[0];
  __syncthreads();
  { float a = 0.0f; for (int k = 0; k < 8; ++k) a += s0[tid*8 + k]; red[tid] = a; }
  __syncthreads();
  for (int st = 256; st > 0; st >>= 1){ if (tid < st) red[tid] += red[tid+st]; __syncthreads(); }
  float Treg = red[0];
  __syncthreads();

  // ---- stage group 0 directly ----
  {
    const float4* Ks = (const float4*)(Kf);
    #pragma unroll
    for (int k = 0; k < 4; ++k){
      int e = tid + k*512;
      float4 vv = Ks[e];
      int gie = e >> 10, row = (e >> 4) & 63, f = e & 15;
      *((float4*)&Kl[gie][row][0] + (f ^ (row & 15))) = vv;
    }
    #pragma unroll
    for (int k = 0; k < 2; ++k){
      int e = tid + k*512;
      int run = e >> 6, tt = e & 63, gie = run >> 3, wl = run & 7;
      cbl[gie][wl][tt] = colbitsP[(size_t)wl*4096 + gie*64 + tt];
    }
    #pragma unroll
    for (int k = 0; k < 2; ++k){
      int e = tid + k*512;
      ((unsigned long long*)xbl)[e] = xbitsW[e];
    }
    #pragma unroll
    for (int k = 0; k < 2; ++k){
      int e = tid + k*512;
      ((float*)Ul)[e] = U[e];
    }
    if (tid < 128){
      ((float4*)cstl)[tid] = cst[tid];
      ((float*)bcl)[tid]   = baseCorr[tid];
    }
  }
  __syncthreads();

  for (int grp = 0; grp < 32; ++grp){
    int ng = grp + 1;
    bool pf = (ng < 32);
    // ---- T14 issue-early: next group's loads into registers ----
    float4 kv0, kv1, kv2, kv3, cstv;
    unsigned long long cbv0, cbv1, xbv0, xbv1;
    float uv0, uv1, bcv;
    if (pf){
      const float4* Ks = (const float4*)(Kf + (size_t)ng*8192);
      kv0 = Ks[tid]; kv1 = Ks[tid+512]; kv2 = Ks[tid+1024]; kv3 = Ks[tid+1536];
      { int e = tid;       int run = e>>6, tt = e&63;
        cbv0 = colbitsP[(size_t)(run&7)*4096 + (ng*2 + (run>>3))*64 + tt]; }
      { int e = tid + 512; int run = e>>6, tt = e&63;
        cbv1 = colbitsP[(size_t)(run&7)*4096 + (ng*2 + (run>>3))*64 + tt]; }
      xbv0 = xbitsW[(size_t)ng*1024 + tid]; xbv1 = xbitsW[(size_t)ng*1024 + tid + 512];
      uv0  = U[(size_t)ng*1024 + tid];      uv1  = U[(size_t)ng*1024 + tid + 512];
      if (tid < 128){ cstv = cst[ng*128 + tid]; bcv = baseCorr[ng*128 + tid]; }
    }

    #pragma unroll
    for (int gi = 0; gi < 2; ++gi){
      int b = grp*2 + gi;
      // ---- phase 1 ----
      {
        unsigned long long w = cbl[gi][g][t];
        unsigned int lo = (unsigned)w, hi = (unsigned)(w >> 32);
        const float4* pw = (const float4*)(p + g*64);
        float acc = 0.0f;
        #pragma unroll
        for (int f = 0; f < 16; ++f){
          float4 q = pw[f];
          if (f < 8){
            ACC1(q.x, lo, 4*f+0) ACC1(q.y, lo, 4*f+1)
            ACC1(q.z, lo, 4*f+2) ACC1(q.w, lo, 4*f+3)
          } else {
            ACC1(q.x, hi, 4*f-32) ACC1(q.y, hi, 4*f-31)
            ACC1(q.z, hi, 4*f-30) ACC1(q.w, hi, 4*f-29)
          }
        }
        part[g][t] = acc;
      }
      __syncthreads();                             // B1

      if (g == 0){
        const float4* Kp = (const float4*)&Kl[gi][t][0];
        int sw = t & 15;
        float S = 0.0f;
        #pragma unroll
        for (int gg = 0; gg < 8; ++gg) S += part[gg][t];
        float4 cc = cstl[gi][t];
        float bc_ = bcl[gi][t];
        float v = S - cc.x - rho*Preg - cc.y*Treg - bc_;
        float4 C0 = Kp[0^sw], C1 = Kp[1^sw], C2 = Kp[2^sw];
        unsigned long long sg_ = 0ull;
        BST4(C0, 0);   C0 = Kp[3^sw];
        BST4(C1, 4);   C1 = Kp[4^sw];
        BST4(C2, 8);   C2 = Kp[5^sw];
        BST4(C0, 12);  C0 = Kp[6^sw];
        BST4(C1, 16);  C1 = Kp[7^sw];
        BST4(C2, 20);  C2 = Kp[8^sw];
        BST4(C0, 24);  C0 = Kp[9^sw];
        BST4(C1, 28);  C1 = Kp[10^sw];
        BST4(C2, 32);  C2 = Kp[11^sw];
        BST4(C0, 36);  C0 = Kp[12^sw];
        BST4(C1, 40);  C1 = Kp[13^sw];
        BST4(C2, 44);  C2 = Kp[14^sw];
        BST4(C0, 48);  C0 = Kp[15^sw];
        BST4(C1, 52);
        BST4(C2, 56);
        BST4(C0, 60);
        if (t == 0){ sig = sg_; sbits[b] = sg_; }
        float sv = ((sg_ >> t) & 1ull) ? cc.w : -cc.w;
        float sc = wave_allsum(sv);
        int pcs = __popcll(sg_);
        Preg += sc - bscl[b];
        Treg += (float)(2*pcs - 64) - bs0l[b];
      }
      __syncthreads();                             // B2
      // ---- phase 3 (no B3: p wave-local; part/sig guarded by B1/B2) ----
      {
        unsigned long long sgv = sig;
        int pc = __popcll(xbl[gi][tid] ^ sgv);
        p[tid] = p[tid] + (float)(64 - 2*pc) - Ul[gi][tid];
      }
    }

    // ---- T14 write-late: prefetched registers -> LDS, then group barrier ----
    if (pf){
      { int e = tid;        int gie=e>>10, row=(e>>4)&63, f=e&15;
        *((float4*)&Kl[gie][row][0] + (f ^ (row & 15))) = kv0; }
      { int e = tid + 512;  int gie=e>>10, row=(e>>4)&63, f=e&15;
        *((float4*)&Kl[gie][row][0] + (f ^ (row & 15))) = kv1; }
      { int e = tid + 1024; int gie=e>>10, row=(e>>4)&63, f=e&15;
        *((float4*)&Kl[gie][row][0] + (f ^ (row & 15))) = kv2; }
      { int e = tid + 1536; int gie=e>>10, row=(e>>4)&63, f=e&15;
        *((float4*)&Kl[gie][row][0] + (f ^ (row & 15))) = kv3; }
      { int e = tid;       int run=e>>6, tt=e&63; cbl[run>>3][run&7][tt] = cbv0; }
      { int e = tid + 512; int run=e>>6, tt=e&63; cbl[run>>3][run&7][tt] = cbv1; }
      ((unsigned long long*)xbl)[tid]       = xbv0;
      ((unsigned long long*)xbl)[tid + 512] = xbv1;
      ((float*)Ul)[tid]       = uv0;
      ((float*)Ul)[tid + 512] = uv1;
      if (tid < 128){ ((float4*)cstl)[tid] = cstv; ((float*)bcl)[tid] = bcv; }
    }
    __syncthreads();                               // B4 (group boundary)
  }
}

// ---- exact integer scores + argmax one-hot
__global__ void k_scores(const unsigned long long* __restrict__ xbits,
                         const unsigned long long* __restrict__ sbits,
                         float* __restrict__ out){
  __shared__ unsigned long long sb[64];
  __shared__ int bestkey;
  int tid = threadIdx.x;  // 512
  if (tid < 64) sb[tid] = sbits[tid];
  if (tid == 0) bestkey = -1;
  __syncthreads();
  int acc = 0;
  #pragma unroll
  for (int w = 0; w < 64; ++w)
    acc += __popcll(xbits[(size_t)tid*64 + w] ^ sb[w]);
  int dot = 4096 - 2*acc;
  int ad  = dot < 0 ? -dot : dot;
  int key = (ad << 10) | (511 - tid);
  atomicMax(&bestkey, key);
  __syncthreads();
  int bl = 511 - (bestkey & 1023);
  float val = (float)(bestkey >> 10) * (1.0f/4096.0f);
  out[tid] = (tid == bl) ? val : 0.0f;
}

extern "C" void kernel_launch(void* const* d_in, const int* in_sizes, int n_in,
                              void* d_out, int out_size, void* d_ws, size_t ws_size,
                              hipStream_t stream){
  const float* s0  = (const float*)d_in[0];   // [4096]
  const float* llv = (const float*)d_in[1];   // [512][4096]
  float* out = (float*)d_out;                 // [512]
  char* ws = (char*)d_ws;

  unsigned long long* colbitsP = (unsigned long long*)(ws + OFF_COLB);
  unsigned long long* xbits    = (unsigned long long*)(ws + OFF_XBITS);
  unsigned long long* xbitsW   = (unsigned long long*)(ws + OFF_XBW);
  float*  Kf    = (float*)(ws + OFF_KF);
  float*  bcorr = (float*)(ws + OFF_BCORR);
  float*  U     = (float*)(ws + OFF_U);
  float4* cst   = (float4*)(ws + OFF_CST);
  float*  p0    = (float*)(ws + OFF_P0);
  unsigned long long* sbits = (unsigned long long*)(ws + OFF_SBITS);
  int*    colcnt = (int*)(ws + OFF_CNT);
  float*  hdr   = (float*)(ws + OFF_HDR);
  float*  bS0   = (float*)(ws + OFF_BS0);
  float*  bS0C  = (float*)(ws + OFF_BS0C);

  k_xbits<<<128, 256, 0, stream>>>(llv, xbits, xbitsW);
  k_bitT<<<dim3(8, 64), 64, 0, stream>>>(xbits, colbitsP);
  k_colc<<<16, 256, 0, stream>>>(colbitsP, colcnt);
  k_rho<<<1, 256, 0, stream>>>(colcnt, hdr);
  k_const<<<16, 256, 0, stream>>>(colcnt, hdr, s0, cst);
  k_kdiag<<<64, 256, 0, stream>>>(colbitsP, cst, s0, hdr, Kf, bcorr, bS0, bS0C);
  k_u<<<64, 512, 0, stream>>>(xbits, s0, U);
  k_pinit<<<512, 64, 0, stream>>>(llv, s0, p0);
  k_sweep6<<<1, 512, 0, stream>>>(colbitsP, xbitsW, Kf, bcorr, bS0, bS0C, U, cst, p0, s0, hdr, sbits);
  k_scores<<<1, 512, 0, stream>>>(xbits, sbits, out);
}